// Round 1
// baseline (31452.652 us; speedup 1.0000x reference)
//
#include <hip/hip_runtime.h>
#include <hip/hip_fp16.h>

#define L2E 1.4426950408889634f

// Problem dims
constexpr int Bb = 16, Ss = 128, Ii = 576, Uu = 512, Hh = 256;

// ws offsets (in 4-byte slots)
constexpr int OFF_AC   = 0;              // 262144 uint  (fp16 a,c per edge, swizzled)
constexpr int OFF_W2   = 262144;         // 131072 uint  (fp16 we pairs)
constexpr int OFF_NUMS = 393216;         // 1048576 f32  sensory numerators (B,S,U)
constexpr int OFF_DENS = 1441792;        // 1048576 f32
constexpr int OFF_VBUF = 2490368;        // 8192 f32     per-batch v exchange
constexpr int OFF_CTR  = 2498560;        // 512 uint     barrier counters (padded)
constexpr int OFF_LTC  = 2499072;        // 524288 f32   ltc_out (B,S,H)
constexpr int OFF_Q    = 3023360;        // 524288
constexpr int OFF_K    = 3547648;        // 524288
constexpr int OFF_V    = 4071936;        // 524288
constexpr int OFF_MEM  = 4596224;        // 524288
constexpr int OFF_HID  = 5120512;        // 524288

__device__ __forceinline__ float ex2(float x) { return __builtin_amdgcn_exp2f(x); }
__device__ __forceinline__ float rcpf(float x) { return __builtin_amdgcn_rcpf(x); }

// ---------------- param prep: derive fp16 edge params in scan LDS layout ----------------
__global__ __launch_bounds__(256) void prep_kernel(
    const float* __restrict__ sigma, const float* __restrict__ mu,
    const float* __restrict__ w, const float* __restrict__ erev,
    const float* __restrict__ mask, float* __restrict__ ws)
{
    const int t = threadIdx.x;
    if (blockIdx.x == 0) {                      // zero barrier counters each launch
        ((unsigned*)ws)[OFF_CTR + t] = 0u;
        ((unsigned*)ws)[OFF_CTR + t + 256] = 0u;
    }
    const int p = blockIdx.x * 256 + t;         // [0, 131072) edge-pairs
    const int i2 = p >> 9, jj = p & 511;
    const int slice = jj >> 4, jl = jj & 15;
    unsigned* AC = (unsigned*)ws + OFF_AC;
    unsigned* W2 = (unsigned*)ws + OFF_W2;
    __half weh0, weh1;
    {
        const int i = i2 * 2;
        const int idx = i * 512 + jj;
        const float sg = sigma[idx], m = mu[idx];
        const float wm = w[idx] * mask[idx];
        __half2 ac; ac.x = __float2half_rn(sg * L2E); ac.y = __float2half_rn(sg * m * L2E);
        AC[slice * 8192 + ((i * 16 + jl) ^ (((i >> 5) & 1) << 4))] = __builtin_bit_cast(unsigned, ac);
        weh0 = __float2half_rn(wm * erev[idx]);
    }
    {
        const int i = i2 * 2 + 1;
        const int idx = i * 512 + jj;
        const float sg = sigma[idx], m = mu[idx];
        const float wm = w[idx] * mask[idx];
        __half2 ac; ac.x = __float2half_rn(sg * L2E); ac.y = __float2half_rn(sg * m * L2E);
        AC[slice * 8192 + ((i * 16 + jl) ^ (((i >> 5) & 1) << 4))] = __builtin_bit_cast(unsigned, ac);
        weh1 = __float2half_rn(wm * erev[idx]);
    }
    __half2 wp; wp.x = weh0; wp.y = weh1;
    W2[slice * 4096 + ((i2 * 16 + jl) ^ (((i2 >> 4) & 1) << 4))] = __builtin_bit_cast(unsigned, wp);
}

// ---------------- sensory precompute: w_num_s / w_den_s for all (b,t) ----------------
__global__ __launch_bounds__(256) void sensory_kernel(
    const float* __restrict__ x, const float* __restrict__ inw, const float* __restrict__ inb,
    const float* __restrict__ ssig, const float* __restrict__ smu,
    const float* __restrict__ sw, const float* __restrict__ serev,
    const float* __restrict__ smask, float* __restrict__ ws)
{
    __shared__ float inp[16 * 576];
    __shared__ float part[4096];               // [4][64][8][2]
    const int t = threadIdx.x;
    const int jb = blockIdx.x & 7, pb = blockIdx.x >> 3;
    #pragma unroll
    for (int e = 0; e < 9; ++e) {
        const int id = t + e * 256;            // [0,2304)
        const int off = id * 4;
        const int bs = off / 576, ii = off % 576;
        const float4 xv = *(const float4*)&x[(pb * 16 + bs) * 576 + ii];
        const float4 wv = *(const float4*)&inw[ii];
        const float4 bv = *(const float4*)&inb[ii];
        inp[off + 0] = fmaf(xv.x, wv.x, bv.x);
        inp[off + 1] = fmaf(xv.y, wv.y, bv.y);
        inp[off + 2] = fmaf(xv.z, wv.z, bv.z);
        inp[off + 3] = fmaf(xv.w, wv.w, bv.w);
    }
    __syncthreads();
    const int j = t & 63, c = t >> 6;
    const int jg = jb * 64 + j;
    float num[16], den[16];
    #pragma unroll
    for (int bs = 0; bs < 16; ++bs) { num[bs] = 0.f; den[bs] = 0.f; }
    for (int ii = c * 144; ii < (c + 1) * 144; ++ii) {
        const int pidx = ii * 512 + jg;
        const float sg = ssig[pidx], m = smu[pidx];
        const float wm = sw[pidx] * smask[pidx];
        const float we = wm * serev[pidx];
        const float a = sg * L2E, cc = sg * m * L2E;
        #pragma unroll
        for (int bs = 0; bs < 16; ++bs) {
            const float vv = inp[bs * 576 + ii];
            const float r = rcpf(1.f + ex2(fmaf(-a, vv, cc)));
            num[bs] = fmaf(we, r, num[bs]);
            den[bs] = fmaf(wm, r, den[bs]);
        }
    }
    #pragma unroll
    for (int pass = 0; pass < 2; ++pass) {
        __syncthreads();
        #pragma unroll
        for (int bs = 0; bs < 8; ++bs) {
            part[((c * 64 + j) * 8 + bs) * 2 + 0] = num[pass * 8 + bs];
            part[((c * 64 + j) * 8 + bs) * 2 + 1] = den[pass * 8 + bs];
        }
        __syncthreads();
        #pragma unroll
        for (int qd = 0; qd < 4; ++qd) {
            const int vid = t * 4 + qd;        // [0,1024)
            const int jj2 = vid >> 4, bs = (vid >> 1) & 7, which = vid & 1;
            const float acc =
                part[((0 * 64 + jj2) * 8 + bs) * 2 + which] + part[((1 * 64 + jj2) * 8 + bs) * 2 + which] +
                part[((2 * 64 + jj2) * 8 + bs) * 2 + which] + part[((3 * 64 + jj2) * 8 + bs) * 2 + which];
            const int p = pb * 16 + pass * 8 + bs;
            ws[(which ? OFF_DENS : OFF_NUMS) + p * 512 + jb * 64 + jj2] = acc;
        }
    }
}

// ---------------- persistent LTC scan: 512 WGs = 16 batches x 32 column-slices ----------------
__global__ __launch_bounds__(256) void scan_kernel(
    const float* __restrict__ gleak, const float* __restrict__ vleak,
    const float* __restrict__ cmv,
    const float* __restrict__ outw, const float* __restrict__ outb,
    float* __restrict__ ws, float* __restrict__ dout)
{
    __shared__ unsigned prmAC[8192];   // 32 KB
    __shared__ unsigned prmW2[4096];   // 16 KB
    __shared__ float vlds[512];        // 2 KB
    __shared__ float2 red[64];         // 0.5 KB

    const int t = threadIdx.x;
    const int wg = blockIdx.x;
    const int batch = wg & 15;         // group = same batch -> same XCD under round-robin
    const int slice = wg >> 4;         // [0,32): 16 output columns each
    const int jl = t & 15;
    const int chunk = t >> 4;          // [0,16): 32 presynaptic i each
    const unsigned swz = (unsigned)((chunk & 1) << 4);

    {   // one-time param copy into LDS
        const uint4* sA = (const uint4*)((const unsigned*)ws + OFF_AC) + slice * 2048;
        uint4* dA = (uint4*)prmAC;
        #pragma unroll
        for (int k = 0; k < 8; ++k) dA[t + k * 256] = sA[t + k * 256];
        const uint4* sW = (const uint4*)((const unsigned*)ws + OFF_W2) + slice * 1024;
        uint4* dW = (uint4*)prmW2;
        #pragma unroll
        for (int k = 0; k < 4; ++k) dW[t + k * 256] = sW[t + k * 256];
    }
    vlds[t] = 0.f; vlds[t + 256] = 0.f;

    const bool owner = (t < 16);
    const int j = slice * 16 + (t & 15);
    float gl = 0.f, glvl = 0.f, cmt = 0.f, ow = 0.f, ob = 0.f, vown = 0.f, sn = 0.f, sd = 0.f;
    if (owner) {
        gl = gleak[j]; glvl = gl * vleak[j]; cmt = cmv[j] * 6.f;
        if (j < Hh) { ow = outw[j]; ob = outb[j]; }
    }
    float* vb = ws + OFF_VBUF + batch * Uu;
    unsigned* ctr = (unsigned*)ws + OFF_CTR + batch * 32;
    const float* snb = ws + OFF_NUMS + batch * (Ss * Uu);
    const float* sdb = ws + OFF_DENS + batch * (Ss * Uu);
    float* ltc = ws + OFF_LTC;

    __syncthreads();

    unsigned phase = 0;
    const int ibase = chunk * 32;

    for (int step = 0; step < Ss; ++step) {
        if (owner) { sn = snb[step * Uu + j]; sd = sdb[step * Uu + j]; }
        for (int uf = 0; uf < 6; ++uf) {
            float n0 = 0.f, n1 = 0.f, d0 = 0.f, d1 = 0.f;
            #pragma unroll
            for (int kk = 0; kk < 8; ++kk) {
                const int ib = ibase + kk * 4;
                const float4 v4 = *(const float4*)&vlds[ib];
                const int eb = ib * 16 + jl;
                const int pbi = (ib >> 1) * 16 + jl;
                const unsigned ac0 = prmAC[(unsigned)(eb) ^ swz];
                const unsigned ac1 = prmAC[(unsigned)(eb + 16) ^ swz];
                const unsigned ac2 = prmAC[(unsigned)(eb + 32) ^ swz];
                const unsigned ac3 = prmAC[(unsigned)(eb + 48) ^ swz];
                const unsigned wp0 = prmW2[(unsigned)(pbi) ^ swz];
                const unsigned wp1 = prmW2[(unsigned)(pbi + 16) ^ swz];
                const float2 w01 = __half22float2(__builtin_bit_cast(__half2, wp0));
                const float2 w23 = __half22float2(__builtin_bit_cast(__half2, wp1));
                {
                    const float2 ac = __half22float2(__builtin_bit_cast(__half2, ac0));
                    const float r = rcpf(1.f + ex2(fmaf(-ac.x, v4.x, ac.y)));
                    n0 = fmaf(w01.x, r, n0); d0 = fmaf(fabsf(w01.x), r, d0);
                }
                {
                    const float2 ac = __half22float2(__builtin_bit_cast(__half2, ac1));
                    const float r = rcpf(1.f + ex2(fmaf(-ac.x, v4.y, ac.y)));
                    n1 = fmaf(w01.y, r, n1); d1 = fmaf(fabsf(w01.y), r, d1);
                }
                {
                    const float2 ac = __half22float2(__builtin_bit_cast(__half2, ac2));
                    const float r = rcpf(1.f + ex2(fmaf(-ac.x, v4.z, ac.y)));
                    n0 = fmaf(w23.x, r, n0); d0 = fmaf(fabsf(w23.x), r, d0);
                }
                {
                    const float2 ac = __half22float2(__builtin_bit_cast(__half2, ac3));
                    const float r = rcpf(1.f + ex2(fmaf(-ac.x, v4.w, ac.y)));
                    n1 = fmaf(w23.y, r, n1); d1 = fmaf(fabsf(w23.y), r, d1);
                }
            }
            float num = n0 + n1, den = d0 + d1;
            num += __shfl_xor(num, 16, 64); den += __shfl_xor(den, 16, 64);
            num += __shfl_xor(num, 32, 64); den += __shfl_xor(den, 32, 64);
            const int lane = t & 63, wave = t >> 6;
            if (lane < 16) red[wave * 16 + lane] = make_float2(num, den);
            __syncthreads();
            if (owner) {
                float rn = sn, rd = sd;
                #pragma unroll
                for (int wv = 0; wv < 4; ++wv) { const float2 pp = red[wv * 16 + t]; rn += pp.x; rd += pp.y; }
                const float vnew = (fmaf(cmt, vown, glvl) + rn) * rcpf(cmt + gl + rd + 1e-8f);
                vown = vnew;
                __hip_atomic_store(vb + j, vnew, __ATOMIC_RELAXED, __HIP_MEMORY_SCOPE_AGENT);
            }
            __threadfence();
            __syncthreads();
            ++phase;
            if (t == 0) {
                __hip_atomic_fetch_add(ctr, 1u, __ATOMIC_ACQ_REL, __HIP_MEMORY_SCOPE_AGENT);
                const unsigned target = phase * 32u;
                while (__hip_atomic_load(ctr, __ATOMIC_ACQUIRE, __HIP_MEMORY_SCOPE_AGENT) < target) {
                    __builtin_amdgcn_s_sleep(2);
                }
            }
            __syncthreads();
            const float va = __hip_atomic_load(vb + t, __ATOMIC_RELAXED, __HIP_MEMORY_SCOPE_AGENT);
            const float vc = __hip_atomic_load(vb + t + 256, __ATOMIC_RELAXED, __HIP_MEMORY_SCOPE_AGENT);
            vlds[t] = va; vlds[t + 256] = vc;
            __syncthreads();
        }
        if (owner && j < Hh) ltc[(batch * Ss + step) * Hh + j] = fmaf(vown, ow, ob);
    }
    if (owner) dout[524288 + 131072 + batch * Uu + j] = vown;
}

// ---------------- generic fp32 tiled GEMM, K=256. MODE: 0 bias, 1 qkv-permute, 2 +residual, 3 silu ----------------
template <int MODE>
__global__ __launch_bounds__(256) void gemm_kernel(
    const float* __restrict__ A, const float* __restrict__ W,
    const float* __restrict__ bias, const float* __restrict__ R,
    float* __restrict__ C, const int N, const float scale)
{
    __shared__ float As[16][64];
    __shared__ float Bs[16][64];
    const int t = threadIdx.x;
    const int tx = t & 15, ty = t >> 4;
    const int by = blockIdx.x, bx = blockIdx.y;
    float acc[4][4] = {{0.f}};
    constexpr int K = 256;
    for (int k0 = 0; k0 < K; k0 += 16) {
        {
            const int r = t >> 2, c4 = (t & 3) << 2;
            const float4 a4 = *(const float4*)&A[(by * 64 + r) * K + k0 + c4];
            As[c4 + 0][r] = a4.x; As[c4 + 1][r] = a4.y; As[c4 + 2][r] = a4.z; As[c4 + 3][r] = a4.w;
        }
        {
            const int r = t >> 4, c4 = (t & 15) << 2;
            *(float4*)&Bs[r][c4] = *(const float4*)&W[(k0 + r) * N + bx * 64 + c4];
        }
        __syncthreads();
        #pragma unroll
        for (int kk = 0; kk < 16; ++kk) {
            const float4 a4 = *(const float4*)&As[kk][ty << 2];
            const float4 b4 = *(const float4*)&Bs[kk][tx << 2];
            acc[0][0] = fmaf(a4.x, b4.x, acc[0][0]); acc[0][1] = fmaf(a4.x, b4.y, acc[0][1]);
            acc[0][2] = fmaf(a4.x, b4.z, acc[0][2]); acc[0][3] = fmaf(a4.x, b4.w, acc[0][3]);
            acc[1][0] = fmaf(a4.y, b4.x, acc[1][0]); acc[1][1] = fmaf(a4.y, b4.y, acc[1][1]);
            acc[1][2] = fmaf(a4.y, b4.z, acc[1][2]); acc[1][3] = fmaf(a4.y, b4.w, acc[1][3]);
            acc[2][0] = fmaf(a4.z, b4.x, acc[2][0]); acc[2][1] = fmaf(a4.z, b4.y, acc[2][1]);
            acc[2][2] = fmaf(a4.z, b4.z, acc[2][2]); acc[2][3] = fmaf(a4.z, b4.w, acc[2][3]);
            acc[3][0] = fmaf(a4.w, b4.x, acc[3][0]); acc[3][1] = fmaf(a4.w, b4.y, acc[3][1]);
            acc[3][2] = fmaf(a4.w, b4.z, acc[3][2]); acc[3][3] = fmaf(a4.w, b4.w, acc[3][3]);
        }
        __syncthreads();
    }
    const int n0 = bx * 64 + (tx << 2);
    const float4 bv = *(const float4*)&bias[n0];
    #pragma unroll
    for (int i2 = 0; i2 < 4; ++i2) {
        const int m = by * 64 + (ty << 2) + i2;
        float4 o;
        o.x = acc[i2][0] + bv.x; o.y = acc[i2][1] + bv.y;
        o.z = acc[i2][2] + bv.z; o.w = acc[i2][3] + bv.w;
        if (MODE == 1) {
            o.x *= scale; o.y *= scale; o.z *= scale; o.w *= scale;
            const int b = m >> 7, s = m & 127;
            const int h = n0 >> 6, d = n0 & 63;
            *(float4*)&C[((b * 4 + h) * 128 + s) * 64 + d] = o;
        } else if (MODE == 2) {
            const float4 rv = *(const float4*)&R[m * N + n0];
            o.x += rv.x; o.y += rv.y; o.z += rv.z; o.w += rv.w;
            *(float4*)&C[m * N + n0] = o;
        } else if (MODE == 3) {
            o.x = o.x * rcpf(1.f + ex2(-o.x * L2E));
            o.y = o.y * rcpf(1.f + ex2(-o.y * L2E));
            o.z = o.z * rcpf(1.f + ex2(-o.z * L2E));
            o.w = o.w * rcpf(1.f + ex2(-o.w * L2E));
            *(float4*)&C[m * N + n0] = o;
        } else {
            *(float4*)&C[m * N + n0] = o;
        }
    }
}

// ---------------- attention: per (b,h,16-q-rows) block ----------------
__global__ __launch_bounds__(256) void attn_kernel(
    const float* __restrict__ q, const float* __restrict__ k,
    const float* __restrict__ v, float* __restrict__ mem)
{
    __shared__ float KV[128 * 66];
    __shared__ float Qs[16 * 66];
    __shared__ float P[16 * 128];
    const int t = threadIdx.x;
    const int qb = blockIdx.x & 7;
    const int bh = blockIdx.x >> 3;
    const float* qp = q + bh * (128 * 64);
    const float* kp = k + bh * (128 * 64);
    const float* vp = v + bh * (128 * 64);
    {
        const int r = t >> 4, d4 = (t & 15) << 2;
        const float4 x4 = *(const float4*)&qp[(qb * 16 + r) * 64 + d4];
        Qs[r * 66 + d4 + 0] = x4.x; Qs[r * 66 + d4 + 1] = x4.y;
        Qs[r * 66 + d4 + 2] = x4.z; Qs[r * 66 + d4 + 3] = x4.w;
    }
    #pragma unroll
    for (int e = 0; e < 8; ++e) {
        const int id = t + e * 256;
        const int s = id >> 4, d4 = (id & 15) << 2;
        const float4 x4 = *(const float4*)&kp[s * 64 + d4];
        KV[s * 66 + d4 + 0] = x4.x; KV[s * 66 + d4 + 1] = x4.y;
        KV[s * 66 + d4 + 2] = x4.z; KV[s * 66 + d4 + 3] = x4.w;
    }
    __syncthreads();
    const int qi = t >> 4, sc = t & 15;
    float pv[8];
    float mx = -3.4e38f;
    #pragma unroll
    for (int s8 = 0; s8 < 8; ++s8) {
        const int s = s8 * 16 + sc;
        float dot = 0.f;
        #pragma unroll
        for (int d4 = 0; d4 < 16; ++d4) {
            const float4 qv = *(const float4*)&Qs[qi * 66 + d4 * 4];
            const float4 kv = *(const float4*)&KV[s * 66 + d4 * 4];
            dot = fmaf(qv.x, kv.x, dot); dot = fmaf(qv.y, kv.y, dot);
            dot = fmaf(qv.z, kv.z, dot); dot = fmaf(qv.w, kv.w, dot);
        }
        pv[s8] = dot;
        mx = fmaxf(mx, dot);
    }
    #pragma unroll
    for (int off = 1; off < 16; off <<= 1) mx = fmaxf(mx, __shfl_xor(mx, off, 16));
    float sum = 0.f;
    #pragma unroll
    for (int s8 = 0; s8 < 8; ++s8) {
        const int s = s8 * 16 + sc;
        const float p = ex2((pv[s8] - mx) * L2E);
        P[qi * 128 + s] = p;
        sum += p;
    }
    #pragma unroll
    for (int off = 1; off < 16; off <<= 1) sum += __shfl_xor(sum, off, 16);
    const float inv = rcpf(sum);
    __syncthreads();
    #pragma unroll
    for (int e = 0; e < 8; ++e) {
        const int id = t + e * 256;
        const int s = id >> 4, d4 = (id & 15) << 2;
        *(float4*)&KV[s * 64 + d4] = *(const float4*)&vp[s * 64 + d4];
    }
    __syncthreads();
    float4 acc = {0.f, 0.f, 0.f, 0.f};
    for (int s = 0; s < 128; ++s) {
        const float p = P[qi * 128 + s];
        const float4 v4 = *(const float4*)&KV[s * 64 + (sc << 2)];
        acc.x = fmaf(p, v4.x, acc.x); acc.y = fmaf(p, v4.y, acc.y);
        acc.z = fmaf(p, v4.z, acc.z); acc.w = fmaf(p, v4.w, acc.w);
    }
    acc.x *= inv; acc.y *= inv; acc.z *= inv; acc.w *= inv;
    const int b = bh >> 2, h = bh & 3;
    const int m = b * 128 + qb * 16 + qi;
    *(float4*)&mem[m * 256 + h * 64 + (sc << 2)] = acc;
}

extern "C" void kernel_launch(void* const* d_in, const int* in_sizes, int n_in,
                              void* d_out, int out_size, void* d_ws, size_t ws_size,
                              hipStream_t stream)
{
    const float* x     = (const float*)d_in[0];
    const float* inw   = (const float*)d_in[1];
    const float* inb   = (const float*)d_in[2];
    const float* gleak = (const float*)d_in[3];
    const float* vleak = (const float*)d_in[4];
    const float* cm    = (const float*)d_in[5];
    const float* sigma = (const float*)d_in[6];
    const float* mu    = (const float*)d_in[7];
    const float* w     = (const float*)d_in[8];
    const float* erev  = (const float*)d_in[9];
    const float* maskr = (const float*)d_in[10];
    const float* ssig  = (const float*)d_in[11];
    const float* smu   = (const float*)d_in[12];
    const float* sw    = (const float*)d_in[13];
    const float* serev = (const float*)d_in[14];
    const float* smask = (const float*)d_in[15];
    const float* outw  = (const float*)d_in[16];
    const float* outb  = (const float*)d_in[17];
    const float* Wq    = (const float*)d_in[18];
    const float* bq    = (const float*)d_in[19];
    const float* Wk    = (const float*)d_in[20];
    const float* bk    = (const float*)d_in[21];
    const float* Wv    = (const float*)d_in[22];
    const float* bv    = (const float*)d_in[23];
    const float* Wo    = (const float*)d_in[24];
    const float* bo    = (const float*)d_in[25];
    const float* W1    = (const float*)d_in[26];
    const float* b1    = (const float*)d_in[27];
    const float* W2    = (const float*)d_in[28];
    const float* b2    = (const float*)d_in[29];

    float* ws  = (float*)d_ws;
    float* out = (float*)d_out;

    prep_kernel<<<512, 256, 0, stream>>>(sigma, mu, w, erev, maskr, ws);
    sensory_kernel<<<1024, 256, 0, stream>>>(x, inw, inb, ssig, smu, sw, serev, smask, ws);
    scan_kernel<<<512, 256, 0, stream>>>(gleak, vleak, cm, outw, outb, ws, out);

    dim3 gA(32, 4);
    gemm_kernel<1><<<gA, 256, 0, stream>>>(ws + OFF_LTC, Wq, bq, nullptr, ws + OFF_Q, 256, 0.125f);
    gemm_kernel<1><<<gA, 256, 0, stream>>>(ws + OFF_LTC, Wk, bk, nullptr, ws + OFF_K, 256, 1.f);
    gemm_kernel<1><<<gA, 256, 0, stream>>>(ws + OFF_LTC, Wv, bv, nullptr, ws + OFF_V, 256, 1.f);
    attn_kernel<<<512, 256, 0, stream>>>(ws + OFF_Q, ws + OFF_K, ws + OFF_V, ws + OFF_MEM);
    gemm_kernel<2><<<gA, 256, 0, stream>>>(ws + OFF_MEM, Wo, bo, ws + OFF_LTC, out, 256, 1.f);
    gemm_kernel<3><<<gA, 256, 0, stream>>>(out, W1, b1, nullptr, ws + OFF_HID, 256, 1.f);
    dim3 gB(32, 1);
    gemm_kernel<0><<<gB, 256, 0, stream>>>(ws + OFF_HID, W2, b2, nullptr, out + 524288, 64, 1.f);
}

// Round 2
// 2168.096 us; speedup vs baseline: 14.5070x; 14.5070x over previous
//
#include <hip/hip_runtime.h>
#include <hip/hip_fp16.h>

#define L2E 1.4426950408889634f

// Problem dims
constexpr int Bb = 16, Ss = 128, Ii = 576, Uu = 512, Hh = 256;

// ws offsets (in 4-byte slots)
constexpr int OFF_AC   = 0;              // 262144 uint  (fp16 a,c per edge, swizzled)
constexpr int OFF_W2   = 262144;         // 131072 uint  (fp16 we pairs)
constexpr int OFF_NUMS = 393216;         // 1048576 f32  sensory numerators (B,S,U)
constexpr int OFF_DENS = 1441792;        // 1048576 f32
constexpr int OFF_LTC  = 2499072;        // 524288 f32   ltc_out (B,S,H)
constexpr int OFF_Q    = 3023360;        // 524288
constexpr int OFF_K    = 3547648;        // 524288
constexpr int OFF_V    = 4071936;        // 524288
constexpr int OFF_MEM  = 4596224;        // 524288
constexpr int OFF_HID  = 5120512;        // 524288  (first 65536 reused as v-exchange bufs during scan)

constexpr unsigned SENT_U = 0x7FBADBADu;  // NaN payload sentinel — unreachable by the LTC math

__device__ __forceinline__ float ex2(float x) { return __builtin_amdgcn_exp2f(x); }
__device__ __forceinline__ float rcpf(float x) { return __builtin_amdgcn_rcpf(x); }

// ---------------- param prep: derive fp16 edge params in scan LDS layout ----------------
__global__ __launch_bounds__(256) void prep_kernel(
    const float* __restrict__ sigma, const float* __restrict__ mu,
    const float* __restrict__ w, const float* __restrict__ erev,
    const float* __restrict__ mask, float* __restrict__ ws)
{
    const int t = threadIdx.x;
    {   // init v-exchange buffers: [batch][8][512]; ring slot 7 = h0 (zeros), others = sentinel
        const int g = blockIdx.x * 256 + t;
        if (g < 16 * 8 * 512) {
            const int r = (g >> 9) & 7;
            ws[OFF_HID + g] = (r == 7) ? 0.0f : __builtin_bit_cast(float, SENT_U);
        }
    }
    const int p = blockIdx.x * 256 + t;         // [0, 131072) edge-pairs
    const int i2 = p >> 9, jj = p & 511;
    const int slice = jj >> 4, jl = jj & 15;
    unsigned* AC = (unsigned*)ws + OFF_AC;
    unsigned* W2 = (unsigned*)ws + OFF_W2;
    __half weh0, weh1;
    {
        const int i = i2 * 2;
        const int idx = i * 512 + jj;
        const float sg = sigma[idx], m = mu[idx];
        const float wm = w[idx] * mask[idx];
        __half2 ac; ac.x = __float2half_rn(sg * L2E); ac.y = __float2half_rn(sg * m * L2E);
        AC[slice * 8192 + ((i * 16 + jl) ^ (((i >> 5) & 1) << 4))] = __builtin_bit_cast(unsigned, ac);
        weh0 = __float2half_rn(wm * erev[idx]);
    }
    {
        const int i = i2 * 2 + 1;
        const int idx = i * 512 + jj;
        const float sg = sigma[idx], m = mu[idx];
        const float wm = w[idx] * mask[idx];
        __half2 ac; ac.x = __float2half_rn(sg * L2E); ac.y = __float2half_rn(sg * m * L2E);
        AC[slice * 8192 + ((i * 16 + jl) ^ (((i >> 5) & 1) << 4))] = __builtin_bit_cast(unsigned, ac);
        weh1 = __float2half_rn(wm * erev[idx]);
    }
    __half2 wp; wp.x = weh0; wp.y = weh1;
    W2[slice * 4096 + ((i2 * 16 + jl) ^ (((i2 >> 4) & 1) << 4))] = __builtin_bit_cast(unsigned, wp);
}

// ---------------- sensory precompute: w_num_s / w_den_s for all (b,t) ----------------
__global__ __launch_bounds__(256) void sensory_kernel(
    const float* __restrict__ x, const float* __restrict__ inw, const float* __restrict__ inb,
    const float* __restrict__ ssig, const float* __restrict__ smu,
    const float* __restrict__ sw, const float* __restrict__ serev,
    const float* __restrict__ smask, float* __restrict__ ws)
{
    __shared__ float inp[16 * 576];
    __shared__ float part[4096];               // [4][64][8][2]
    const int t = threadIdx.x;
    const int jb = blockIdx.x & 7, pb = blockIdx.x >> 3;
    #pragma unroll
    for (int e = 0; e < 9; ++e) {
        const int id = t + e * 256;            // [0,2304)
        const int off = id * 4;
        const int bs = off / 576, ii = off % 576;
        const float4 xv = *(const float4*)&x[(pb * 16 + bs) * 576 + ii];
        const float4 wv = *(const float4*)&inw[ii];
        const float4 bv = *(const float4*)&inb[ii];
        inp[off + 0] = fmaf(xv.x, wv.x, bv.x);
        inp[off + 1] = fmaf(xv.y, wv.y, bv.y);
        inp[off + 2] = fmaf(xv.z, wv.z, bv.z);
        inp[off + 3] = fmaf(xv.w, wv.w, bv.w);
    }
    __syncthreads();
    const int j = t & 63, c = t >> 6;
    const int jg = jb * 64 + j;
    float num[16], den[16];
    #pragma unroll
    for (int bs = 0; bs < 16; ++bs) { num[bs] = 0.f; den[bs] = 0.f; }
    for (int ii = c * 144; ii < (c + 1) * 144; ++ii) {
        const int pidx = ii * 512 + jg;
        const float sg = ssig[pidx], m = smu[pidx];
        const float wm = sw[pidx] * smask[pidx];
        const float we = wm * serev[pidx];
        const float a = sg * L2E, cc = sg * m * L2E;
        #pragma unroll
        for (int bs = 0; bs < 16; ++bs) {
            const float vv = inp[bs * 576 + ii];
            const float r = rcpf(1.f + ex2(fmaf(-a, vv, cc)));
            num[bs] = fmaf(we, r, num[bs]);
            den[bs] = fmaf(wm, r, den[bs]);
        }
    }
    #pragma unroll
    for (int pass = 0; pass < 2; ++pass) {
        __syncthreads();
        #pragma unroll
        for (int bs = 0; bs < 8; ++bs) {
            part[((c * 64 + j) * 8 + bs) * 2 + 0] = num[pass * 8 + bs];
            part[((c * 64 + j) * 8 + bs) * 2 + 1] = den[pass * 8 + bs];
        }
        __syncthreads();
        #pragma unroll
        for (int qd = 0; qd < 4; ++qd) {
            const int vid = t * 4 + qd;        // [0,1024)
            const int jj2 = vid >> 4, bs = (vid >> 1) & 7, which = vid & 1;
            const float acc =
                part[((0 * 64 + jj2) * 8 + bs) * 2 + which] + part[((1 * 64 + jj2) * 8 + bs) * 2 + which] +
                part[((2 * 64 + jj2) * 8 + bs) * 2 + which] + part[((3 * 64 + jj2) * 8 + bs) * 2 + which];
            const int p = pb * 16 + pass * 8 + bs;
            ws[(which ? OFF_DENS : OFF_NUMS) + p * 512 + jb * 64 + jj2] = acc;
        }
    }
}

// ---------------- persistent LTC scan: 512 WGs = 16 batches x 32 column-slices ----------------
// Cross-WG sync: fence-free sentinel protocol. 8 rotating v-buffers per batch at agent scope
// (sc1 -> coherent at IF$; never needs L2 writeback). Writers fire-and-forget; readers spin
// on their own 2 slots until != sentinel. Skew between WGs of a batch is provably <= 1 phase,
// so resetting buffer (phase+4)&7 during the current phase is race-free (distance 4 vs skew 1,
// mod 8). __syncthreads' implicit vmcnt(0) drain orders reset-store before the v-store.
__global__ __launch_bounds__(256) void scan_kernel(
    const float* __restrict__ gleak, const float* __restrict__ vleak,
    const float* __restrict__ cmv,
    const float* __restrict__ outw, const float* __restrict__ outb,
    float* __restrict__ ws, float* __restrict__ dout)
{
    __shared__ unsigned prmAC[8192];   // 32 KB
    __shared__ unsigned prmW2[4096];   // 16 KB
    __shared__ float vlds[512];        // 2 KB
    __shared__ float2 red[64];         // 0.5 KB

    const int t = threadIdx.x;
    const int wg = blockIdx.x;
    const int batch = wg & 15;
    const int slice = wg >> 4;         // [0,32): 16 output columns each
    const int jl = t & 15;
    const int chunk = t >> 4;          // [0,16): 32 presynaptic i each
    const unsigned swz = (unsigned)((chunk & 1) << 4);

    {   // one-time param copy into LDS
        const uint4* sA = (const uint4*)((const unsigned*)ws + OFF_AC) + slice * 2048;
        uint4* dA = (uint4*)prmAC;
        #pragma unroll
        for (int k = 0; k < 8; ++k) dA[t + k * 256] = sA[t + k * 256];
        const uint4* sW = (const uint4*)((const unsigned*)ws + OFF_W2) + slice * 1024;
        uint4* dW = (uint4*)prmW2;
        #pragma unroll
        for (int k = 0; k < 4; ++k) dW[t + k * 256] = sW[t + k * 256];
    }

    const bool owner = (t < 16);
    const int j = slice * 16 + jl;
    float gl = 0.f, glvl = 0.f, cmt = 0.f, ow = 0.f, ob = 0.f, vown = 0.f, sn = 0.f, sd = 0.f;
    if (owner) {
        gl = gleak[j]; glvl = gl * vleak[j]; cmt = cmv[j] * 6.f;
        if (j < Hh) { ow = outw[j]; ob = outb[j]; }
    }
    float* vb2 = ws + OFF_HID + batch * 4096;      // [8][512] ring
    const float* snb = ws + OFF_NUMS + batch * (Ss * Uu);
    const float* sdb = ws + OFF_DENS + batch * (Ss * Uu);
    float* ltc = ws + OFF_LTC;

    __syncthreads();

    unsigned phase = 0;
    const int ibase = chunk * 32;

    for (int step = 0; step < Ss; ++step) {
        if (owner) { sn = snb[step * Uu + j]; sd = sdb[step * Uu + j]; }
        for (int uf = 0; uf < 6; ++uf) {
            // (a) reset the buffer that will carry phase+4 (its last readers are >=3 phases done)
            if (owner) {
                __hip_atomic_store(vb2 + (((phase + 4) & 7) << 9) + j,
                                   __builtin_bit_cast(float, SENT_U),
                                   __ATOMIC_RELAXED, __HIP_MEMORY_SCOPE_AGENT);
            }
            // (b) spin for v_{phase-1} directly on the data (2 slots per thread)
            {
                const float* src = vb2 + (((phase + 7) & 7) << 9);
                float va = 0.f, vc = 0.f;
                unsigned ua = SENT_U, uc = SENT_U;
                do {
                    if (ua == SENT_U) {
                        va = __hip_atomic_load(src + t, __ATOMIC_RELAXED, __HIP_MEMORY_SCOPE_AGENT);
                        ua = __builtin_bit_cast(unsigned, va);
                    }
                    if (uc == SENT_U) {
                        vc = __hip_atomic_load(src + t + 256, __ATOMIC_RELAXED, __HIP_MEMORY_SCOPE_AGENT);
                        uc = __builtin_bit_cast(unsigned, vc);
                    }
                } while (ua == SENT_U || uc == SENT_U);
                vlds[t] = va; vlds[t + 256] = vc;
            }
            __syncthreads();

            float n0 = 0.f, n1 = 0.f, d0 = 0.f, d1 = 0.f;
            #pragma unroll
            for (int kk = 0; kk < 8; ++kk) {
                const int ib = ibase + kk * 4;
                const float4 v4 = *(const float4*)&vlds[ib];
                const int eb = ib * 16 + jl;
                const int pbi = (ib >> 1) * 16 + jl;
                const unsigned ac0 = prmAC[(unsigned)(eb) ^ swz];
                const unsigned ac1 = prmAC[(unsigned)(eb + 16) ^ swz];
                const unsigned ac2 = prmAC[(unsigned)(eb + 32) ^ swz];
                const unsigned ac3 = prmAC[(unsigned)(eb + 48) ^ swz];
                const unsigned wp0 = prmW2[(unsigned)(pbi) ^ swz];
                const unsigned wp1 = prmW2[(unsigned)(pbi + 16) ^ swz];
                const float2 w01 = __half22float2(__builtin_bit_cast(__half2, wp0));
                const float2 w23 = __half22float2(__builtin_bit_cast(__half2, wp1));
                {
                    const float2 ac = __half22float2(__builtin_bit_cast(__half2, ac0));
                    const float r = rcpf(1.f + ex2(fmaf(-ac.x, v4.x, ac.y)));
                    n0 = fmaf(w01.x, r, n0); d0 = fmaf(fabsf(w01.x), r, d0);
                }
                {
                    const float2 ac = __half22float2(__builtin_bit_cast(__half2, ac1));
                    const float r = rcpf(1.f + ex2(fmaf(-ac.x, v4.y, ac.y)));
                    n1 = fmaf(w01.y, r, n1); d1 = fmaf(fabsf(w01.y), r, d1);
                }
                {
                    const float2 ac = __half22float2(__builtin_bit_cast(__half2, ac2));
                    const float r = rcpf(1.f + ex2(fmaf(-ac.x, v4.z, ac.y)));
                    n0 = fmaf(w23.x, r, n0); d0 = fmaf(fabsf(w23.x), r, d0);
                }
                {
                    const float2 ac = __half22float2(__builtin_bit_cast(__half2, ac3));
                    const float r = rcpf(1.f + ex2(fmaf(-ac.x, v4.w, ac.y)));
                    n1 = fmaf(w23.y, r, n1); d1 = fmaf(fabsf(w23.y), r, d1);
                }
            }
            float num = n0 + n1, den = d0 + d1;
            num += __shfl_xor(num, 16, 64); den += __shfl_xor(den, 16, 64);
            num += __shfl_xor(num, 32, 64); den += __shfl_xor(den, 32, 64);
            const int lane = t & 63, wave = t >> 6;
            if (lane < 16) red[wave * 16 + lane] = make_float2(num, den);
            __syncthreads();
            if (owner) {
                float rn = sn, rd = sd;
                #pragma unroll
                for (int wv = 0; wv < 4; ++wv) { const float2 pp = red[wv * 16 + t]; rn += pp.x; rd += pp.y; }
                const float vnew = (fmaf(cmt, vown, glvl) + rn) * rcpf(cmt + gl + rd + 1e-8f);
                vown = vnew;
                __hip_atomic_store(vb2 + ((phase & 7) << 9) + j, vnew,
                                   __ATOMIC_RELAXED, __HIP_MEMORY_SCOPE_AGENT);
            }
            ++phase;
        }
        if (owner && j < Hh) ltc[(batch * Ss + step) * Hh + j] = fmaf(vown, ow, ob);
    }
    if (owner) dout[524288 + 131072 + batch * Uu + j] = vown;
}

// ---------------- generic fp32 tiled GEMM, K=256. MODE: 0 bias, 1 qkv-permute, 2 +residual, 3 silu ----------------
template <int MODE>
__global__ __launch_bounds__(256) void gemm_kernel(
    const float* __restrict__ A, const float* __restrict__ W,
    const float* __restrict__ bias, const float* __restrict__ R,
    float* __restrict__ C, const int N, const float scale)
{
    __shared__ float As[16][64];
    __shared__ float Bs[16][64];
    const int t = threadIdx.x;
    const int tx = t & 15, ty = t >> 4;
    const int by = blockIdx.x, bx = blockIdx.y;
    float acc[4][4] = {{0.f}};
    constexpr int K = 256;
    for (int k0 = 0; k0 < K; k0 += 16) {
        {
            const int r = t >> 2, c4 = (t & 3) << 2;
            const float4 a4 = *(const float4*)&A[(by * 64 + r) * K + k0 + c4];
            As[c4 + 0][r] = a4.x; As[c4 + 1][r] = a4.y; As[c4 + 2][r] = a4.z; As[c4 + 3][r] = a4.w;
        }
        {
            const int r = t >> 4, c4 = (t & 15) << 2;
            *(float4*)&Bs[r][c4] = *(const float4*)&W[(k0 + r) * N + bx * 64 + c4];
        }
        __syncthreads();
        #pragma unroll
        for (int kk = 0; kk < 16; ++kk) {
            const float4 a4 = *(const float4*)&As[kk][ty << 2];
            const float4 b4 = *(const float4*)&Bs[kk][tx << 2];
            acc[0][0] = fmaf(a4.x, b4.x, acc[0][0]); acc[0][1] = fmaf(a4.x, b4.y, acc[0][1]);
            acc[0][2] = fmaf(a4.x, b4.z, acc[0][2]); acc[0][3] = fmaf(a4.x, b4.w, acc[0][3]);
            acc[1][0] = fmaf(a4.y, b4.x, acc[1][0]); acc[1][1] = fmaf(a4.y, b4.y, acc[1][1]);
            acc[1][2] = fmaf(a4.y, b4.z, acc[1][2]); acc[1][3] = fmaf(a4.y, b4.w, acc[1][3]);
            acc[2][0] = fmaf(a4.z, b4.x, acc[2][0]); acc[2][1] = fmaf(a4.z, b4.y, acc[2][1]);
            acc[2][2] = fmaf(a4.z, b4.z, acc[2][2]); acc[2][3] = fmaf(a4.z, b4.w, acc[2][3]);
            acc[3][0] = fmaf(a4.w, b4.x, acc[3][0]); acc[3][1] = fmaf(a4.w, b4.y, acc[3][1]);
            acc[3][2] = fmaf(a4.w, b4.z, acc[3][2]); acc[3][3] = fmaf(a4.w, b4.w, acc[3][3]);
        }
        __syncthreads();
    }
    const int n0 = bx * 64 + (tx << 2);
    const float4 bv = *(const float4*)&bias[n0];
    #pragma unroll
    for (int i2 = 0; i2 < 4; ++i2) {
        const int m = by * 64 + (ty << 2) + i2;
        float4 o;
        o.x = acc[i2][0] + bv.x; o.y = acc[i2][1] + bv.y;
        o.z = acc[i2][2] + bv.z; o.w = acc[i2][3] + bv.w;
        if (MODE == 1) {
            o.x *= scale; o.y *= scale; o.z *= scale; o.w *= scale;
            const int b = m >> 7, s = m & 127;
            const int h = n0 >> 6, d = n0 & 63;
            *(float4*)&C[((b * 4 + h) * 128 + s) * 64 + d] = o;
        } else if (MODE == 2) {
            const float4 rv = *(const float4*)&R[m * N + n0];
            o.x += rv.x; o.y += rv.y; o.z += rv.z; o.w += rv.w;
            *(float4*)&C[m * N + n0] = o;
        } else if (MODE == 3) {
            o.x = o.x * rcpf(1.f + ex2(-o.x * L2E));
            o.y = o.y * rcpf(1.f + ex2(-o.y * L2E));
            o.z = o.z * rcpf(1.f + ex2(-o.z * L2E));
            o.w = o.w * rcpf(1.f + ex2(-o.w * L2E));
            *(float4*)&C[m * N + n0] = o;
        } else {
            *(float4*)&C[m * N + n0] = o;
        }
    }
}

// ---------------- attention: per (b,h,16-q-rows) block ----------------
__global__ __launch_bounds__(256) void attn_kernel(
    const float* __restrict__ q, const float* __restrict__ k,
    const float* __restrict__ v, float* __restrict__ mem)
{
    __shared__ float KV[128 * 66];
    __shared__ float Qs[16 * 66];
    __shared__ float P[16 * 128];
    const int t = threadIdx.x;
    const int qb = blockIdx.x & 7;
    const int bh = blockIdx.x >> 3;
    const float* qp = q + bh * (128 * 64);
    const float* kp = k + bh * (128 * 64);
    const float* vp = v + bh * (128 * 64);
    {
        const int r = t >> 4, d4 = (t & 15) << 2;
        const float4 x4 = *(const float4*)&qp[(qb * 16 + r) * 64 + d4];
        Qs[r * 66 + d4 + 0] = x4.x; Qs[r * 66 + d4 + 1] = x4.y;
        Qs[r * 66 + d4 + 2] = x4.z; Qs[r * 66 + d4 + 3] = x4.w;
    }
    #pragma unroll
    for (int e = 0; e < 8; ++e) {
        const int id = t + e * 256;
        const int s = id >> 4, d4 = (id & 15) << 2;
        const float4 x4 = *(const float4*)&kp[s * 64 + d4];
        KV[s * 66 + d4 + 0] = x4.x; KV[s * 66 + d4 + 1] = x4.y;
        KV[s * 66 + d4 + 2] = x4.z; KV[s * 66 + d4 + 3] = x4.w;
    }
    __syncthreads();
    const int qi = t >> 4, sc = t & 15;
    float pv[8];
    float mx = -3.4e38f;
    #pragma unroll
    for (int s8 = 0; s8 < 8; ++s8) {
        const int s = s8 * 16 + sc;
        float dot = 0.f;
        #pragma unroll
        for (int d4 = 0; d4 < 16; ++d4) {
            const float4 qv = *(const float4*)&Qs[qi * 66 + d4 * 4];
            const float4 kv = *(const float4*)&KV[s * 66 + d4 * 4];
            dot = fmaf(qv.x, kv.x, dot); dot = fmaf(qv.y, kv.y, dot);
            dot = fmaf(qv.z, kv.z, dot); dot = fmaf(qv.w, kv.w, dot);
        }
        pv[s8] = dot;
        mx = fmaxf(mx, dot);
    }
    #pragma unroll
    for (int off = 1; off < 16; off <<= 1) mx = fmaxf(mx, __shfl_xor(mx, off, 16));
    float sum = 0.f;
    #pragma unroll
    for (int s8 = 0; s8 < 8; ++s8) {
        const int s = s8 * 16 + sc;
        const float p = ex2((pv[s8] - mx) * L2E);
        P[qi * 128 + s] = p;
        sum += p;
    }
    #pragma unroll
    for (int off = 1; off < 16; off <<= 1) sum += __shfl_xor(sum, off, 16);
    const float inv = rcpf(sum);
    __syncthreads();
    #pragma unroll
    for (int e = 0; e < 8; ++e) {
        const int id = t + e * 256;
        const int s = id >> 4, d4 = (id & 15) << 2;
        *(float4*)&KV[s * 64 + d4] = *(const float4*)&vp[s * 64 + d4];
    }
    __syncthreads();
    float4 acc = {0.f, 0.f, 0.f, 0.f};
    for (int s = 0; s < 128; ++s) {
        const float p = P[qi * 128 + s];
        const float4 v4 = *(const float4*)&KV[s * 64 + (sc << 2)];
        acc.x = fmaf(p, v4.x, acc.x); acc.y = fmaf(p, v4.y, acc.y);
        acc.z = fmaf(p, v4.z, acc.z); acc.w = fmaf(p, v4.w, acc.w);
    }
    acc.x *= inv; acc.y *= inv; acc.z *= inv; acc.w *= inv;
    const int b = bh >> 2, h = bh & 3;
    const int m = b * 128 + qb * 16 + qi;
    *(float4*)&mem[m * 256 + h * 64 + (sc << 2)] = acc;
}

extern "C" void kernel_launch(void* const* d_in, const int* in_sizes, int n_in,
                              void* d_out, int out_size, void* d_ws, size_t ws_size,
                              hipStream_t stream)
{
    const float* x     = (const float*)d_in[0];
    const float* inw   = (const float*)d_in[1];
    const float* inb   = (const float*)d_in[2];
    const float* gleak = (const float*)d_in[3];
    const float* vleak = (const float*)d_in[4];
    const float* cm    = (const float*)d_in[5];
    const float* sigma = (const float*)d_in[6];
    const float* mu    = (const float*)d_in[7];
    const float* w     = (const float*)d_in[8];
    const float* erev  = (const float*)d_in[9];
    const float* maskr = (const float*)d_in[10];
    const float* ssig  = (const float*)d_in[11];
    const float* smu   = (const float*)d_in[12];
    const float* sw    = (const float*)d_in[13];
    const float* serev = (const float*)d_in[14];
    const float* smask = (const float*)d_in[15];
    const float* outw  = (const float*)d_in[16];
    const float* outb  = (const float*)d_in[17];
    const float* Wq    = (const float*)d_in[18];
    const float* bq    = (const float*)d_in[19];
    const float* Wk    = (const float*)d_in[20];
    const float* bk    = (const float*)d_in[21];
    const float* Wv    = (const float*)d_in[22];
    const float* bv    = (const float*)d_in[23];
    const float* Wo    = (const float*)d_in[24];
    const float* bo    = (const float*)d_in[25];
    const float* W1    = (const float*)d_in[26];
    const float* b1    = (const float*)d_in[27];
    const float* W2    = (const float*)d_in[28];
    const float* b2    = (const float*)d_in[29];

    float* ws  = (float*)d_ws;
    float* out = (float*)d_out;

    prep_kernel<<<512, 256, 0, stream>>>(sigma, mu, w, erev, maskr, ws);
    sensory_kernel<<<1024, 256, 0, stream>>>(x, inw, inb, ssig, smu, sw, serev, smask, ws);
    scan_kernel<<<512, 256, 0, stream>>>(gleak, vleak, cm, outw, outb, ws, out);

    dim3 gA(32, 4);
    gemm_kernel<1><<<gA, 256, 0, stream>>>(ws + OFF_LTC, Wq, bq, nullptr, ws + OFF_Q, 256, 0.125f);
    gemm_kernel<1><<<gA, 256, 0, stream>>>(ws + OFF_LTC, Wk, bk, nullptr, ws + OFF_K, 256, 1.f);
    gemm_kernel<1><<<gA, 256, 0, stream>>>(ws + OFF_LTC, Wv, bv, nullptr, ws + OFF_V, 256, 1.f);
    attn_kernel<<<512, 256, 0, stream>>>(ws + OFF_Q, ws + OFF_K, ws + OFF_V, ws + OFF_MEM);
    gemm_kernel<2><<<gA, 256, 0, stream>>>(ws + OFF_MEM, Wo, bo, ws + OFF_LTC, out, 256, 1.f);
    gemm_kernel<3><<<gA, 256, 0, stream>>>(out, W1, b1, nullptr, ws + OFF_HID, 256, 1.f);
    dim3 gB(32, 1);
    gemm_kernel<0><<<gB, 256, 0, stream>>>(ws + OFF_HID, W2, b2, nullptr, out + 524288, 64, 1.f);
}

// Round 3
// 2138.904 us; speedup vs baseline: 14.7050x; 1.0136x over previous
//
#include <hip/hip_runtime.h>
#include <hip/hip_fp16.h>

#define L2E 1.4426950408889634f

// Problem dims
constexpr int Bb = 16, Ss = 128, Ii = 576, Uu = 512, Hh = 256;

// ws offsets (in 4-byte slots)
constexpr int OFF_AC   = 0;              // 262144 uint  half2(a,c) col-major [j][i]
constexpr int OFF_W2   = 262144;         // 131072 uint  half2(we_2p, we_2p+1) [j][p]
constexpr int OFF_NUMS = 393216;         // 1048576 f32  sensory numerators (B,S,U)
constexpr int OFF_DENS = 1441792;        // 1048576 f32
constexpr int OFF_LTC  = 2499072;        // 524288 f32   ltc_out (B,S,H)
constexpr int OFF_Q    = 3023360;        // 524288
constexpr int OFF_K    = 3547648;        // 524288
constexpr int OFF_V    = 4071936;        // 524288
constexpr int OFF_MEM  = 4596224;        // 524288
constexpr int OFF_HID  = 5120512;        // 524288  (first 65536 reused as v-ring during scan)

constexpr unsigned SENT_U = 0x7FBADBADu;  // NaN-payload sentinel, unreachable by the LTC math

__device__ __forceinline__ float ex2(float x) { return __builtin_amdgcn_exp2f(x); }
__device__ __forceinline__ float rcpf(float x) { return __builtin_amdgcn_rcpf(x); }

// ---------------- param prep: fp16 edge params, column-major for per-lane register load ----------------
__global__ __launch_bounds__(256) void prep_kernel(
    const float* __restrict__ sigma, const float* __restrict__ mu,
    const float* __restrict__ w, const float* __restrict__ erev,
    const float* __restrict__ mask, float* __restrict__ ws)
{
    const int t = threadIdx.x;
    const int g = blockIdx.x * 256 + t;         // [0, 131072)
    // ring init: [batch][8][512]; slot 7 = h0 zeros, others = sentinel
    if (g < 16 * 8 * 512) {
        const int r = (g >> 9) & 7;
        ws[OFF_HID + g] = (r == 7) ? 0.0f : __builtin_bit_cast(float, SENT_U);
    }
    const int j = g >> 8;                       // column [0,512)
    const int p = g & 255;                      // row-pair [0,256)
    const int i0 = p * 2, i1 = p * 2 + 1;
    unsigned* AC = (unsigned*)ws + OFF_AC;
    unsigned* W2 = (unsigned*)ws + OFF_W2;
    const int x0 = i0 * 512 + j, x1 = i1 * 512 + j;
    const float sg0 = sigma[x0], m0 = mu[x0];
    const float wm0 = w[x0] * mask[x0], we0 = wm0 * erev[x0];
    const float sg1 = sigma[x1], m1 = mu[x1];
    const float wm1 = w[x1] * mask[x1], we1 = wm1 * erev[x1];
    __half2 ac0; ac0.x = __float2half_rn(sg0 * L2E); ac0.y = __float2half_rn(sg0 * m0 * L2E);
    __half2 ac1; ac1.x = __float2half_rn(sg1 * L2E); ac1.y = __float2half_rn(sg1 * m1 * L2E);
    AC[j * 512 + i0] = __builtin_bit_cast(unsigned, ac0);
    AC[j * 512 + i1] = __builtin_bit_cast(unsigned, ac1);
    __half2 wp; wp.x = __float2half_rn(we0); wp.y = __float2half_rn(we1);
    W2[j * 256 + p] = __builtin_bit_cast(unsigned, wp);
}

// ---------------- sensory precompute: w_num_s / w_den_s for all (b,t) ----------------
__global__ __launch_bounds__(256) void sensory_kernel(
    const float* __restrict__ x, const float* __restrict__ inw, const float* __restrict__ inb,
    const float* __restrict__ ssig, const float* __restrict__ smu,
    const float* __restrict__ sw, const float* __restrict__ serev,
    const float* __restrict__ smask, float* __restrict__ ws)
{
    __shared__ float inp[16 * 576];
    __shared__ float part[4096];               // [4][64][8][2]
    const int t = threadIdx.x;
    const int jb = blockIdx.x & 7, pb = blockIdx.x >> 3;
    #pragma unroll
    for (int e = 0; e < 9; ++e) {
        const int id = t + e * 256;            // [0,2304)
        const int off = id * 4;
        const int bs = off / 576, ii = off % 576;
        const float4 xv = *(const float4*)&x[(pb * 16 + bs) * 576 + ii];
        const float4 wv = *(const float4*)&inw[ii];
        const float4 bv = *(const float4*)&inb[ii];
        inp[off + 0] = fmaf(xv.x, wv.x, bv.x);
        inp[off + 1] = fmaf(xv.y, wv.y, bv.y);
        inp[off + 2] = fmaf(xv.z, wv.z, bv.z);
        inp[off + 3] = fmaf(xv.w, wv.w, bv.w);
    }
    __syncthreads();
    const int j = t & 63, c = t >> 6;
    const int jg = jb * 64 + j;
    float num[16], den[16];
    #pragma unroll
    for (int bs = 0; bs < 16; ++bs) { num[bs] = 0.f; den[bs] = 0.f; }
    for (int ii = c * 144; ii < (c + 1) * 144; ++ii) {
        const int pidx = ii * 512 + jg;
        const float sg = ssig[pidx], m = smu[pidx];
        const float wm = sw[pidx] * smask[pidx];
        const float we = wm * serev[pidx];
        const float a = sg * L2E, cc = sg * m * L2E;
        #pragma unroll
        for (int bs = 0; bs < 16; ++bs) {
            const float vv = inp[bs * 576 + ii];
            const float r = rcpf(1.f + ex2(fmaf(-a, vv, cc)));
            num[bs] = fmaf(we, r, num[bs]);
            den[bs] = fmaf(wm, r, den[bs]);
        }
    }
    #pragma unroll
    for (int pass = 0; pass < 2; ++pass) {
        __syncthreads();
        #pragma unroll
        for (int bs = 0; bs < 8; ++bs) {
            part[((c * 64 + j) * 8 + bs) * 2 + 0] = num[pass * 8 + bs];
            part[((c * 64 + j) * 8 + bs) * 2 + 1] = den[pass * 8 + bs];
        }
        __syncthreads();
        #pragma unroll
        for (int qd = 0; qd < 4; ++qd) {
            const int vid = t * 4 + qd;        // [0,1024)
            const int jj2 = vid >> 4, bs = (vid >> 1) & 7, which = vid & 1;
            const float acc =
                part[((0 * 64 + jj2) * 8 + bs) * 2 + which] + part[((1 * 64 + jj2) * 8 + bs) * 2 + which] +
                part[((2 * 64 + jj2) * 8 + bs) * 2 + which] + part[((3 * 64 + jj2) * 8 + bs) * 2 + which];
            const int p = pb * 16 + pass * 8 + bs;
            ws[(which ? OFF_DENS : OFF_NUMS) + p * 512 + jb * 64 + jj2] = acc;
        }
    }
}

// ---------------- persistent LTC scan v3: wave-autonomous, reg-resident params ----------------
// 512 WGs = 16 batches x 32 slices(16 cols). Wave owns 4 complete columns:
// lane = colL*16 + rg; lane handles rows rg*32..+32 of column j. num/den reduce =
// 4-step shfl_xor within 16 lanes -> no LDS reduction, ONE barrier per phase (vlds dbuf).
// Edge params live in 48 VGPRs/lane for all 768 phases. Sentinel-ring sync as round-2
// (reset at distance 4; skew <= ~1.5 phases since a wave past its spin implies every
// owner stored phase-1).
__global__ __launch_bounds__(256) void scan_kernel(
    const float* __restrict__ gleak, const float* __restrict__ vleak,
    const float* __restrict__ cmv,
    const float* __restrict__ outw, const float* __restrict__ outb,
    float* __restrict__ ws, float* __restrict__ dout)
{
    __shared__ float vlds[2][512];     // 4 KB, double-buffered, bank-XOR-swizzled

    const int t = threadIdx.x;
    const int wg = blockIdx.x;
    const int batch = wg & 15;
    const int slice = wg >> 4;
    const int lane = t & 63;
    const int wv = t >> 6;
    const int colL = lane >> 4;        // 0..3
    const int rg = lane & 15;          // 0..15 (rows rg*32..+32)
    const int j = slice * 16 + wv * 4 + colL;
    const bool owner = (rg == 0);

    // one-time: edge params into registers (32 ac + 16 we-pairs per lane)
    unsigned ac[32], wep[16];
    {
        const unsigned* ACg = (const unsigned*)ws + OFF_AC + j * 512 + rg * 32;
        #pragma unroll
        for (int q = 0; q < 8; ++q) {
            const uint4 u = ((const uint4*)ACg)[q];
            ac[q * 4 + 0] = u.x; ac[q * 4 + 1] = u.y; ac[q * 4 + 2] = u.z; ac[q * 4 + 3] = u.w;
        }
        const unsigned* WEg = (const unsigned*)ws + OFF_W2 + j * 256 + rg * 16;
        #pragma unroll
        for (int q = 0; q < 4; ++q) {
            const uint4 u = ((const uint4*)WEg)[q];
            wep[q * 4 + 0] = u.x; wep[q * 4 + 1] = u.y; wep[q * 4 + 2] = u.z; wep[q * 4 + 3] = u.w;
        }
    }
    float gl = 0.f, glvl = 0.f, cmt = 0.f, ow = 0.f, ob = 0.f, vown = 0.f, sn = 0.f, sd = 0.f;
    if (owner) {
        gl = gleak[j]; glvl = gl * vleak[j]; cmt = cmv[j] * 6.f;
        if (j < Hh) { ow = outw[j]; ob = outb[j]; }
    }
    float* ring = ws + OFF_HID + batch * 4096;   // [8][512]
    const float* snb = ws + OFF_NUMS + batch * (Ss * Uu);
    const float* sdb = ws + OFF_DENS + batch * (Ss * Uu);
    float* ltc = ws + OFF_LTC;

    const int sw0 = t ^ (((t >> 5) & 7) << 2);   // swizzled vlds index for slot t (and t+256: +256)

    unsigned phase = 0;
    int buf = 0;

    for (int step = 0; step < Ss; ++step) {
        if (owner) { sn = snb[step * Uu + j]; sd = sdb[step * Uu + j]; }
        for (int uf = 0; uf < 6; ++uf) {
            // (a) reset ring slot phase+4 (readers of it are >= 3 phases done)
            if (owner) {
                __hip_atomic_store(ring + (((phase + 4) & 7) << 9) + j,
                                   __builtin_bit_cast(float, SENT_U),
                                   __ATOMIC_RELAXED, __HIP_MEMORY_SCOPE_AGENT);
            }
            // (b) spin on v_{phase-1}: 2 slots/thread, conditional reload
            {
                const float* src = ring + (((phase + 7) & 7) << 9);
                float va = 0.f, vc = 0.f;
                unsigned ua = SENT_U, uc = SENT_U;
                do {
                    if (ua == SENT_U) {
                        va = __hip_atomic_load(src + t, __ATOMIC_RELAXED, __HIP_MEMORY_SCOPE_AGENT);
                        ua = __builtin_bit_cast(unsigned, va);
                    }
                    if (uc == SENT_U) {
                        vc = __hip_atomic_load(src + t + 256, __ATOMIC_RELAXED, __HIP_MEMORY_SCOPE_AGENT);
                        uc = __builtin_bit_cast(unsigned, vc);
                    }
                } while (ua == SENT_U || uc == SENT_U);
                vlds[buf][sw0] = va; vlds[buf][sw0 + 256] = vc;
            }
            __syncthreads();   // the ONLY barrier per phase (dbuf covers WAR)

            float n0 = 0.f, n1 = 0.f, d0 = 0.f, d1 = 0.f;
            const float* vb = vlds[buf];
            float2 wef = make_float2(0.f, 0.f);
            #pragma unroll
            for (int k4 = 0; k4 < 8; ++k4) {
                const int idx = (rg * 32 + k4 * 4) ^ ((rg & 7) << 2);
                const float4 v4 = *(const float4*)&vb[idx];
                #pragma unroll
                for (int kk = 0; kk < 4; ++kk) {
                    const int k = k4 * 4 + kk;
                    const float vi = (kk == 0) ? v4.x : (kk == 1) ? v4.y : (kk == 2) ? v4.z : v4.w;
                    const float2 a = __half22float2(__builtin_bit_cast(__half2, ac[k]));
                    const float r = rcpf(1.f + ex2(fmaf(-a.x, vi, a.y)));
                    if ((k & 1) == 0) {
                        wef = __half22float2(__builtin_bit_cast(__half2, wep[k >> 1]));
                        n0 = fmaf(wef.x, r, n0); d0 = fmaf(fabsf(wef.x), r, d0);
                    } else {
                        n1 = fmaf(wef.y, r, n1); d1 = fmaf(fabsf(wef.y), r, d1);
                    }
                }
            }
            float n = n0 + n1, d = d0 + d1;
            n += __shfl_xor(n, 1, 64); d += __shfl_xor(d, 1, 64);
            n += __shfl_xor(n, 2, 64); d += __shfl_xor(d, 2, 64);
            n += __shfl_xor(n, 4, 64); d += __shfl_xor(d, 4, 64);
            n += __shfl_xor(n, 8, 64); d += __shfl_xor(d, 8, 64);
            if (owner) {
                const float rn = n + sn, rd = d + sd;
                const float vnew = (fmaf(cmt, vown, glvl) + rn) * rcpf(cmt + gl + rd + 1e-8f);
                vown = vnew;
                __hip_atomic_store(ring + ((phase & 7) << 9) + j, vnew,
                                   __ATOMIC_RELAXED, __HIP_MEMORY_SCOPE_AGENT);
            }
            ++phase; buf ^= 1;
        }
        if (owner && j < Hh) ltc[(batch * Ss + step) * Hh + j] = fmaf(vown, ow, ob);
    }
    if (owner) dout[524288 + 131072 + batch * Uu + j] = vown;
}

// ---------------- generic fp32 tiled GEMM, K=256. MODE: 0 bias, 1 qkv-permute, 2 +residual, 3 silu ----------------
template <int MODE>
__global__ __launch_bounds__(256) void gemm_kernel(
    const float* __restrict__ A, const float* __restrict__ W,
    const float* __restrict__ bias, const float* __restrict__ R,
    float* __restrict__ C, const int N, const float scale)
{
    __shared__ float As[16][64];
    __shared__ float Bs[16][64];
    const int t = threadIdx.x;
    const int tx = t & 15, ty = t >> 4;
    const int by = blockIdx.x, bx = blockIdx.y;
    float acc[4][4] = {{0.f}};
    constexpr int K = 256;
    for (int k0 = 0; k0 < K; k0 += 16) {
        {
            const int r = t >> 2, c4 = (t & 3) << 2;
            const float4 a4 = *(const float4*)&A[(by * 64 + r) * K + k0 + c4];
            As[c4 + 0][r] = a4.x; As[c4 + 1][r] = a4.y; As[c4 + 2][r] = a4.z; As[c4 + 3][r] = a4.w;
        }
        {
            const int r = t >> 4, c4 = (t & 15) << 2;
            *(float4*)&Bs[r][c4] = *(const float4*)&W[(k0 + r) * N + bx * 64 + c4];
        }
        __syncthreads();
        #pragma unroll
        for (int kk = 0; kk < 16; ++kk) {
            const float4 a4 = *(const float4*)&As[kk][ty << 2];
            const float4 b4 = *(const float4*)&Bs[kk][tx << 2];
            acc[0][0] = fmaf(a4.x, b4.x, acc[0][0]); acc[0][1] = fmaf(a4.x, b4.y, acc[0][1]);
            acc[0][2] = fmaf(a4.x, b4.z, acc[0][2]); acc[0][3] = fmaf(a4.x, b4.w, acc[0][3]);
            acc[1][0] = fmaf(a4.y, b4.x, acc[1][0]); acc[1][1] = fmaf(a4.y, b4.y, acc[1][1]);
            acc[1][2] = fmaf(a4.y, b4.z, acc[1][2]); acc[1][3] = fmaf(a4.y, b4.w, acc[1][3]);
            acc[2][0] = fmaf(a4.z, b4.x, acc[2][0]); acc[2][1] = fmaf(a4.z, b4.y, acc[2][1]);
            acc[2][2] = fmaf(a4.z, b4.z, acc[2][2]); acc[2][3] = fmaf(a4.z, b4.w, acc[2][3]);
            acc[3][0] = fmaf(a4.w, b4.x, acc[3][0]); acc[3][1] = fmaf(a4.w, b4.y, acc[3][1]);
            acc[3][2] = fmaf(a4.w, b4.z, acc[3][2]); acc[3][3] = fmaf(a4.w, b4.w, acc[3][3]);
        }
        __syncthreads();
    }
    const int n0 = bx * 64 + (tx << 2);
    const float4 bv = *(const float4*)&bias[n0];
    #pragma unroll
    for (int i2 = 0; i2 < 4; ++i2) {
        const int m = by * 64 + (ty << 2) + i2;
        float4 o;
        o.x = acc[i2][0] + bv.x; o.y = acc[i2][1] + bv.y;
        o.z = acc[i2][2] + bv.z; o.w = acc[i2][3] + bv.w;
        if (MODE == 1) {
            o.x *= scale; o.y *= scale; o.z *= scale; o.w *= scale;
            const int b = m >> 7, s = m & 127;
            const int h = n0 >> 6, d = n0 & 63;
            *(float4*)&C[((b * 4 + h) * 128 + s) * 64 + d] = o;
        } else if (MODE == 2) {
            const float4 rv = *(const float4*)&R[m * N + n0];
            o.x += rv.x; o.y += rv.y; o.z += rv.z; o.w += rv.w;
            *(float4*)&C[m * N + n0] = o;
        } else if (MODE == 3) {
            o.x = o.x * rcpf(1.f + ex2(-o.x * L2E));
            o.y = o.y * rcpf(1.f + ex2(-o.y * L2E));
            o.z = o.z * rcpf(1.f + ex2(-o.z * L2E));
            o.w = o.w * rcpf(1.f + ex2(-o.w * L2E));
            *(float4*)&C[m * N + n0] = o;
        } else {
            *(float4*)&C[m * N + n0] = o;
        }
    }
}

// ---------------- attention: per (b,h,16-q-rows) block ----------------
__global__ __launch_bounds__(256) void attn_kernel(
    const float* __restrict__ q, const float* __restrict__ k,
    const float* __restrict__ v, float* __restrict__ mem)
{
    __shared__ float KV[128 * 66];
    __shared__ float Qs[16 * 66];
    __shared__ float P[16 * 128];
    const int t = threadIdx.x;
    const int qb = blockIdx.x & 7;
    const int bh = blockIdx.x >> 3;
    const float* qp = q + bh * (128 * 64);
    const float* kp = k + bh * (128 * 64);
    const float* vp = v + bh * (128 * 64);
    {
        const int r = t >> 4, d4 = (t & 15) << 2;
        const float4 x4 = *(const float4*)&qp[(qb * 16 + r) * 64 + d4];
        Qs[r * 66 + d4 + 0] = x4.x; Qs[r * 66 + d4 + 1] = x4.y;
        Qs[r * 66 + d4 + 2] = x4.z; Qs[r * 66 + d4 + 3] = x4.w;
    }
    #pragma unroll
    for (int e = 0; e < 8; ++e) {
        const int id = t + e * 256;
        const int s = id >> 4, d4 = (id & 15) << 2;
        const float4 x4 = *(const float4*)&kp[s * 64 + d4];
        KV[s * 66 + d4 + 0] = x4.x; KV[s * 66 + d4 + 1] = x4.y;
        KV[s * 66 + d4 + 2] = x4.z; KV[s * 66 + d4 + 3] = x4.w;
    }
    __syncthreads();
    const int qi = t >> 4, sc = t & 15;
    float pv[8];
    float mx = -3.4e38f;
    #pragma unroll
    for (int s8 = 0; s8 < 8; ++s8) {
        const int s = s8 * 16 + sc;
        float dot = 0.f;
        #pragma unroll
        for (int d4 = 0; d4 < 16; ++d4) {
            const float4 qv = *(const float4*)&Qs[qi * 66 + d4 * 4];
            const float4 kv = *(const float4*)&KV[s * 66 + d4 * 4];
            dot = fmaf(qv.x, kv.x, dot); dot = fmaf(qv.y, kv.y, dot);
            dot = fmaf(qv.z, kv.z, dot); dot = fmaf(qv.w, kv.w, dot);
        }
        pv[s8] = dot;
        mx = fmaxf(mx, dot);
    }
    #pragma unroll
    for (int off = 1; off < 16; off <<= 1) mx = fmaxf(mx, __shfl_xor(mx, off, 16));
    float sum = 0.f;
    #pragma unroll
    for (int s8 = 0; s8 < 8; ++s8) {
        const int s = s8 * 16 + sc;
        const float p = ex2((pv[s8] - mx) * L2E);
        P[qi * 128 + s] = p;
        sum += p;
    }
    #pragma unroll
    for (int off = 1; off < 16; off <<= 1) sum += __shfl_xor(sum, off, 16);
    const float inv = rcpf(sum);
    __syncthreads();
    #pragma unroll
    for (int e = 0; e < 8; ++e) {
        const int id = t + e * 256;
        const int s = id >> 4, d4 = (id & 15) << 2;
        *(float4*)&KV[s * 64 + d4] = *(const float4*)&vp[s * 64 + d4];
    }
    __syncthreads();
    float4 acc = {0.f, 0.f, 0.f, 0.f};
    for (int s = 0; s < 128; ++s) {
        const float p = P[qi * 128 + s];
        const float4 v4 = *(const float4*)&KV[s * 64 + (sc << 2)];
        acc.x = fmaf(p, v4.x, acc.x); acc.y = fmaf(p, v4.y, acc.y);
        acc.z = fmaf(p, v4.z, acc.z); acc.w = fmaf(p, v4.w, acc.w);
    }
    acc.x *= inv; acc.y *= inv; acc.z *= inv; acc.w *= inv;
    const int b = bh >> 2, h = bh & 3;
    const int m = b * 128 + qb * 16 + qi;
    *(float4*)&mem[m * 256 + h * 64 + (sc << 2)] = acc;
}

extern "C" void kernel_launch(void* const* d_in, const int* in_sizes, int n_in,
                              void* d_out, int out_size, void* d_ws, size_t ws_size,
                              hipStream_t stream)
{
    const float* x     = (const float*)d_in[0];
    const float* inw   = (const float*)d_in[1];
    const float* inb   = (const float*)d_in[2];
    const float* gleak = (const float*)d_in[3];
    const float* vleak = (const float*)d_in[4];
    const float* cm    = (const float*)d_in[5];
    const float* sigma = (const float*)d_in[6];
    const float* mu    = (const float*)d_in[7];
    const float* w     = (const float*)d_in[8];
    const float* erev  = (const float*)d_in[9];
    const float* maskr = (const float*)d_in[10];
    const float* ssig  = (const float*)d_in[11];
    const float* smu   = (const float*)d_in[12];
    const float* sw    = (const float*)d_in[13];
    const float* serev = (const float*)d_in[14];
    const float* smask = (const float*)d_in[15];
    const float* outw  = (const float*)d_in[16];
    const float* outb  = (const float*)d_in[17];
    const float* Wq    = (const float*)d_in[18];
    const float* bq    = (const float*)d_in[19];
    const float* Wk    = (const float*)d_in[20];
    const float* bk    = (const float*)d_in[21];
    const float* Wv    = (const float*)d_in[22];
    const float* bv    = (const float*)d_in[23];
    const float* Wo    = (const float*)d_in[24];
    const float* bo    = (const float*)d_in[25];
    const float* W1    = (const float*)d_in[26];
    const float* b1    = (const float*)d_in[27];
    const float* W2    = (const float*)d_in[28];
    const float* b2    = (const float*)d_in[29];

    float* ws  = (float*)d_ws;
    float* out = (float*)d_out;

    prep_kernel<<<512, 256, 0, stream>>>(sigma, mu, w, erev, maskr, ws);
    sensory_kernel<<<1024, 256, 0, stream>>>(x, inw, inb, ssig, smu, sw, serev, smask, ws);
    scan_kernel<<<512, 256, 0, stream>>>(gleak, vleak, cm, outw, outb, ws, out);

    dim3 gA(32, 4);
    gemm_kernel<1><<<gA, 256, 0, stream>>>(ws + OFF_LTC, Wq, bq, nullptr, ws + OFF_Q, 256, 0.125f);
    gemm_kernel<1><<<gA, 256, 0, stream>>>(ws + OFF_LTC, Wk, bk, nullptr, ws + OFF_K, 256, 1.f);
    gemm_kernel<1><<<gA, 256, 0, stream>>>(ws + OFF_LTC, Wv, bv, nullptr, ws + OFF_V, 256, 1.f);
    attn_kernel<<<512, 256, 0, stream>>>(ws + OFF_Q, ws + OFF_K, ws + OFF_V, ws + OFF_MEM);
    gemm_kernel<2><<<gA, 256, 0, stream>>>(ws + OFF_MEM, Wo, bo, ws + OFF_LTC, out, 256, 1.f);
    gemm_kernel<3><<<gA, 256, 0, stream>>>(out, W1, b1, nullptr, ws + OFF_HID, 256, 1.f);
    dim3 gB(32, 1);
    gemm_kernel<0><<<gB, 256, 0, stream>>>(ws + OFF_HID, W2, b2, nullptr, out + 524288, 64, 1.f);
}